// Round 1
// baseline (103.230 us; speedup 1.0000x reference)
//
#include <hip/hip_runtime.h>
#include <math.h>

// Problem constants: B,F,C,H,W,D
constexpr int B_ = 2, F_ = 2, C_ = 64, H_ = 32, W_ = 104, D_ = 96;
constexpr int HW_ = H_ * W_;             // 3328
#define EPSF 1e-7f

// Workspace layout:
//   lfT  [B,F,H,W,C]  bf16 (ushort)  channel-last lookup feats  -- R12: bf16 halves L2 corner traffic
//   curT [B,H,W,C]    f32            channel-last current feats
constexpr size_t LFT_ELEMS  = (size_t)B_ * F_ * HW_ * C_;   // 851968 ushorts = 1,703,936 B
constexpr size_t CURT_OFF_F = LFT_ELEMS / 2;                // 425984 floats (byte offset identical)

constexpr int NT_BLKS = (HW_ / 32) * (C_ / 32) * (B_ * F_ + B_);  // 1248
constexpr int PXB   = 4;        // pixels per block — 16B stores + reuse sweet spot (R10: PXB=2 => 9x write amp)
constexpr int XT_   = W_ / PXB; // 26 x-tiles
constexpr int DPAD  = D_ + 1;   // 97: float4 row stride
constexpr int DPADI = D_ + 4;   // 100: int row stride (multiple of 4 -> int4 rows stay 16B aligned)

// DPP butterfly add over 16-lane group — bit-identical to __shfl_xor chain
// (only commutes IEEE add operands). VALU-only: no ds_swizzle latency.
template<int CTRL>
__device__ __forceinline__ float dpp_add(float x) {
    int y = __builtin_amdgcn_update_dpp(0, __float_as_int(x), CTRL, 0xf, 0xf, true);
    return x + __int_as_float(y);
}
__device__ __forceinline__ float group16_sum(float s) {
    s = dpp_add<0xB1>(s);    // quad_perm(1,0,3,2)  == + lane^1
    s = dpp_add<0x4E>(s);    // quad_perm(2,3,0,1)  == + lane^2
    s = dpp_add<0x141>(s);   // row_half_mirror     == + lane^4-equiv
    s = dpp_add<0x140>(s);   // row_mirror          == + lane^8-equiv
    return s;
}

// f32 -> bf16 with round-to-nearest-even (features are finite; no NaN path needed)
__device__ __forceinline__ ushort f2bf(float f) {
    unsigned u = __float_as_uint(f);
    u += 0x7FFFu + ((u >> 16) & 1u);
    return (ushort)(u >> 16);
}
// unpack 4 consecutive bf16 channels (one uint2) to float4
__device__ __forceinline__ float4 bf4(uint2 q) {
    return make_float4(__uint_as_float(q.x << 16),
                       __uint_as_float(q.x & 0xffff0000u),
                       __uint_as_float(q.y << 16),
                       __uint_as_float(q.y & 0xffff0000u));
}

// ---------------------------------------------------------------------------
// Prep: channel-last transpose [C, HW] -> [HW, C] for 6 slices.
// lf slices (0..3) are written as bf16; cur slices (4..5) stay f32.
__global__ __launch_bounds__(256) void prep_kernel(
        const float* __restrict__ cur, const float* __restrict__ lf,
        float* __restrict__ ws) {
    __shared__ float tile[32][33];
    int bid = blockIdx.x;
    int slice = bid / 208;            // 208 = 104 n-blocks * 2 c-blocks
    int rem   = bid % 208;
    int nb = rem % 104, cb = rem / 104;
    const float* inS = (slice < B_ * F_)
        ? lf  + (size_t)slice * C_ * HW_
        : cur + (size_t)(slice - B_ * F_) * C_ * HW_;
    int t = threadIdx.x;
    int tx = t & 31, ty = t >> 5;
    int n0 = nb * 32, c0 = cb * 32;
    #pragma unroll
    for (int k = 0; k < 32; k += 8)
        tile[ty + k][tx] = inS[(size_t)(c0 + ty + k) * HW_ + n0 + tx];
    __syncthreads();
    if (slice < B_ * F_) {
        ushort* outS = (ushort*)ws + (size_t)slice * HW_ * C_;
        #pragma unroll
        for (int k = 0; k < 32; k += 8)
            outS[(size_t)(n0 + ty + k) * C_ + c0 + tx] = f2bf(tile[tx][ty + k]);
    } else {
        float* outS = ws + CURT_OFF_F + (size_t)(slice - B_ * F_) * HW_ * C_;
        #pragma unroll
        for (int k = 0; k < 32; k += 8)
            outS[(size_t)(n0 + ty + k) * C_ + c0 + tx] = tile[tx][ty + k];
    }
}

// ---------------------------------------------------------------------------
// Mega kernel: block = (b, y, xt) covering 4 px * ALL 96 depths * 2 frames.
// 256 threads = 4 halves x (16 lanes x 4 px); each half walks 24 depths.
// Phase A: 768 projections -> LDS {offset, float4 weights}  (bit-identical
//          FP op order to R9/R11 — mask-critical, do not touch).
// Phase B: d-walk in 4-depth groups (int4 offset batch); bf16 corner uint2s
//          unpacked into a float4 VGPR cache keyed on offset (dedup);
//          channel reduce via fma chain folding -cv + DPP; cost via v_rcp.
// Phase C: in-block missing-fill (cost==0 -> column max) + store.
__global__ __launch_bounds__(256, 6) void mega_kernel(
        const float* __restrict__ poses, const float* __restrict__ K,
        const float* __restrict__ invK, const float* __restrict__ depth_bins,
        const float* __restrict__ ws, float* __restrict__ out) {
    int t   = threadIdx.x;
    int bid = blockIdx.x;
    int xt  = bid % XT_;  int r = bid / XT_;
    int y   = r % H_;
    int b   = r / H_;

    if (y < 2 || y >= H_ - 2) {
        // whole row masked: cost column all-zero -> column max 0 -> output 0
        for (int k = t; k < PXB * D_; k += 256) {
            int d = k >> 2, px = k & 3;
            out[((size_t)(b * D_ + d) * H_ + y) * W_ + xt * PXB + px] = 0.0f;
        }
        return;   // block-uniform exit
    }

    __shared__ alignas(16) int offsL[F_][PXB][DPADI];
    __shared__ float4 wtsL [F_][PXB][DPAD];
    __shared__ float  costb[PXB][DPAD];
    __shared__ float  pmax[32][PXB];
    __shared__ float  cmaxb[PXB];

    // ---- Phase A: projections (FP op order identical to R9/R11) ----
    {
        // px = (t + 256k) & 3 = t & 3 — invariant across k. Hoist cam/interior.
        int pxA = t & 3;
        int xA  = xt * PXB + pxA;
        const float* iK = invK + (size_t)b * 16;
        float xf = (float)xA, yf = (float)y;
        float cam0 = __fmul_rn(iK[0], xf); cam0 = __fmaf_rn(iK[1], yf, cam0); cam0 = __fmaf_rn(iK[2],  1.0f, cam0);
        float cam1 = __fmul_rn(iK[4], xf); cam1 = __fmaf_rn(iK[5], yf, cam1); cam1 = __fmaf_rn(iK[6],  1.0f, cam1);
        float cam2 = __fmul_rn(iK[8], xf); cam2 = __fmaf_rn(iK[9], yf, cam2); cam2 = __fmaf_rn(iK[10], 1.0f, cam2);
        bool interior = (xA >= 2) && (xA <= W_ - 3);   // y already interior

        #pragma unroll
        for (int f = 0; f < F_; ++f) {
            const float* Kb   = K + (size_t)b * 16;
            const float* pose = poses + (size_t)(b * F_ + f) * 16;
            float P[12];
            #pragma unroll
            for (int i = 0; i < 3; ++i) {
                #pragma unroll
                for (int k = 0; k < 4; ++k) {
                    float acc = __fmul_rn(Kb[i*4+0], pose[0*4+k]);
                    acc = __fmaf_rn(Kb[i*4+1], pose[1*4+k], acc);
                    acc = __fmaf_rn(Kb[i*4+2], pose[2*4+k], acc);
                    acc = __fmaf_rn(Kb[i*4+3], pose[3*4+k], acc);
                    P[i*4+k] = acc;
                }
            }
            float vs = 0.f;
            #pragma unroll
            for (int j = 0; j < 16; ++j) vs += pose[j];
            bool valid = (vs != 0.f);

            #pragma unroll
            for (int k = 0; k < 2; ++k) {
                int idx = t + 256 * k;          // records [0,384) = dd*4 + px
                if (idx < PXB * D_) {
                    int dd = idx >> 2;
                    float depth = depth_bins[dd];
                    float p0 = __fmul_rn(depth, cam0);
                    float p1 = __fmul_rn(depth, cam1);
                    float p2 = __fmul_rn(depth, cam2);
                    float c0 = __fmul_rn(P[0], p0); c0 = __fmaf_rn(P[1], p1, c0); c0 = __fmaf_rn(P[2],  p2, c0); c0 = __fmaf_rn(P[3],  1.0f, c0);
                    float c1 = __fmul_rn(P[4], p0); c1 = __fmaf_rn(P[5], p1, c1); c1 = __fmaf_rn(P[6],  p2, c1); c1 = __fmaf_rn(P[7],  1.0f, c1);
                    float c2 = __fmul_rn(P[8], p0); c2 = __fmaf_rn(P[9], p1, c2); c2 = __fmaf_rn(P[10], p2, c2); c2 = __fmaf_rn(P[11], 1.0f, c2);
                    float denom = __fadd_rn(c2, EPSF);
                    float gx = c0 / denom;   // IEEE div — mask-critical
                    float gy = c1 / denom;
                    bool m = valid && interior && (gx >= 2.0f) && (gx <= (float)(W_ - 2))
                                               && (gy >= 2.0f) && (gy <= (float)(H_ - 2));
                    if (m) {
                        float x0f = floorf(gx), y0f = floorf(gy);
                        int   x0  = (int)x0f,   y0  = (int)y0f;
                        float wx1 = gx - x0f, wy1 = gy - y0f;
                        float wx0 = 1.f - wx1, wy0 = 1.f - wy1;
                        wtsL[f][pxA][dd] = make_float4(wy0 * wx0, wy0 * wx1,
                                                       wy1 * wx0, wy1 * wx1);
                        offsL[f][pxA][dd] = (y0 * W_ + x0) * C_;   // element offset (ushort units)
                    } else {
                        offsL[f][pxA][dd] = -1;
                        // NaN-safety: weights MUST be finite (diff = s*0; 0*NaN=NaN).
                        wtsL[f][pxA][dd] = make_float4(0.f, 0.f, 0.f, 0.f);
                    }
                }
            }
        }
    }
    __syncthreads();

    // ---- Phase B: sampling; bf16 loads + VGPR corner cache + DPP reduce ----
    {
        int lane = t & 15, px = (t >> 4) & 3, half = t >> 6;  // half in [0,4)
        int x = xt * PXB + px;
        const float4 cv = *(const float4*)(ws + CURT_OFF_F
                            + ((size_t)((b * H_ + y) * W_ + x)) * C_ + lane * 4);
        // two bases per frame: row y0 and row y0+1 (col x0+1 is +C_ = 128B imm)
        const ushort* lfbase = (const ushort*)ws;
        const ushort* lf0a = lfbase + (size_t)(b * F_ + 0) * HW_ * C_ + lane * 4;
        const ushort* lf0b = lf0a + W_ * C_;
        const ushort* lf1a = lfbase + (size_t)(b * F_ + 1) * HW_ * C_ + lane * 4;
        const ushort* lf1b = lf1a + W_ * C_;

        float4 cc0[4], cc1[4];
        int oprev0 = -1, oprev1 = -1;
        #pragma unroll
        for (int k = 0; k < 4; ++k)
            cc0[k] = cc1[k] = make_float4(0.f, 0.f, 0.f, 0.f);

        int dbeg = half * (D_ / 4);
        for (int ki4 = 0; ki4 < D_ / 16; ++ki4) {     // 6 groups of 4 depths
            int dc4 = dbeg + ki4 * 4;
            int4 oq0 = *(const int4*)&offsL[0][px][dc4];   // one ds_read_b128 / frame / 4 depths
            int4 oq1 = *(const int4*)&offsL[1][px][dc4];
            int oa0[4] = {oq0.x, oq0.y, oq0.z, oq0.w};     // static-indexed below (stays in VGPRs)
            int oa1[4] = {oq1.x, oq1.y, oq1.z, oq1.w};

            #pragma unroll
            for (int j = 0; j < 4; ++j) {
                int dc = dc4 + j;
                int    oc0 = oa0[j],          oc1 = oa1[j];
                float4 wc0 = wtsL[0][px][dc], wc1 = wtsL[1][px][dc];

                float costsum = 0.f, counts = 0.f;
                // f = 0
                {
                    bool m = (oc0 >= 0);
                    if (m && oc0 != oprev0) {     // 16-lane-group-uniform branch
                        uint2 q0 = *(const uint2*)(lf0a + oc0);
                        uint2 q1 = *(const uint2*)(lf0a + oc0 + C_);
                        uint2 q2 = *(const uint2*)(lf0b + oc0);
                        uint2 q3 = *(const uint2*)(lf0b + oc0 + C_);
                        cc0[0] = bf4(q0); cc0[1] = bf4(q1); cc0[2] = bf4(q2); cc0[3] = bf4(q3);
                        oprev0 = oc0;
                    }
                    // -cv folded into fma chain (saves the separate subtract;
                    // masked case: wc0==0 -> a=-cv, killed by the m-multiply)
                    float a0 = __fmaf_rn(cc0[0].x, wc0.x, __fmaf_rn(cc0[1].x, wc0.y, __fmaf_rn(cc0[2].x, wc0.z, __fmaf_rn(cc0[3].x, wc0.w, -cv.x))));
                    float a1 = __fmaf_rn(cc0[0].y, wc0.x, __fmaf_rn(cc0[1].y, wc0.y, __fmaf_rn(cc0[2].y, wc0.z, __fmaf_rn(cc0[3].y, wc0.w, -cv.y))));
                    float a2 = __fmaf_rn(cc0[0].z, wc0.x, __fmaf_rn(cc0[1].z, wc0.y, __fmaf_rn(cc0[2].z, wc0.z, __fmaf_rn(cc0[3].z, wc0.w, -cv.z))));
                    float a3 = __fmaf_rn(cc0[0].w, wc0.x, __fmaf_rn(cc0[1].w, wc0.y, __fmaf_rn(cc0[2].w, wc0.z, __fmaf_rn(cc0[3].w, wc0.w, -cv.w))));
                    float s = (fabsf(a0) + fabsf(a1)) + (fabsf(a2) + fabsf(a3));
                    s = group16_sum(s);
                    float diff = __fmul_rn(s, 1.0f / 64.0f) * (m ? 1.0f : 0.0f);
                    costsum += diff;
                    counts  += (diff > 0.f) ? 1.0f : 0.0f;
                }
                // f = 1
                {
                    bool m = (oc1 >= 0);
                    if (m && oc1 != oprev1) {
                        uint2 q0 = *(const uint2*)(lf1a + oc1);
                        uint2 q1 = *(const uint2*)(lf1a + oc1 + C_);
                        uint2 q2 = *(const uint2*)(lf1b + oc1);
                        uint2 q3 = *(const uint2*)(lf1b + oc1 + C_);
                        cc1[0] = bf4(q0); cc1[1] = bf4(q1); cc1[2] = bf4(q2); cc1[3] = bf4(q3);
                        oprev1 = oc1;
                    }
                    float a0 = __fmaf_rn(cc1[0].x, wc1.x, __fmaf_rn(cc1[1].x, wc1.y, __fmaf_rn(cc1[2].x, wc1.z, __fmaf_rn(cc1[3].x, wc1.w, -cv.x))));
                    float a1 = __fmaf_rn(cc1[0].y, wc1.x, __fmaf_rn(cc1[1].y, wc1.y, __fmaf_rn(cc1[2].y, wc1.z, __fmaf_rn(cc1[3].y, wc1.w, -cv.y))));
                    float a2 = __fmaf_rn(cc1[0].z, wc1.x, __fmaf_rn(cc1[1].z, wc1.y, __fmaf_rn(cc1[2].z, wc1.z, __fmaf_rn(cc1[3].z, wc1.w, -cv.z))));
                    float a3 = __fmaf_rn(cc1[0].w, wc1.x, __fmaf_rn(cc1[1].w, wc1.y, __fmaf_rn(cc1[2].w, wc1.z, __fmaf_rn(cc1[3].w, wc1.w, -cv.w))));
                    float s = (fabsf(a0) + fabsf(a1)) + (fabsf(a2) + fabsf(a3));
                    s = group16_sum(s);
                    float diff = __fmul_rn(s, 1.0f / 64.0f) * (m ? 1.0f : 0.0f);
                    costsum += diff;
                    counts  += (diff > 0.f) ? 1.0f : 0.0f;
                }
                // cost via fast rcp: ~1e-7 rel err (bf16 threshold 2.9e-2), and
                // EXACT zero preserved (costsum==0 -> 0*rcp(eps)=0) so the ==0.0
                // missing-fill semantics are unchanged.
                float cost = costsum * __builtin_amdgcn_rcpf(__fadd_rn(counts, EPSF));
                if (lane == 0) costb[px][dc] = cost;
            }
        }
    }
    __syncthreads();

    // ---- Phase C: missing-fill + store (first 128 threads own the data) ----
    {
        int j = t >> 2, px = t & 3;          // j in [0,64); only j<32 used
        float v[3];
        if (t < 128) {
            float pm = 0.f;
            #pragma unroll
            for (int k = 0; k < 3; ++k) {
                v[k] = costb[px][j + 32 * k];
                pm = fmaxf(pm, v[k]);
            }
            pmax[j][px] = pm;
        }
        __syncthreads();
        if (t < PXB) {
            float cm = 0.f;
            #pragma unroll
            for (int jj = 0; jj < 32; ++jj) cm = fmaxf(cm, pmax[jj][t]);
            cmaxb[t] = cm;
        }
        __syncthreads();
        if (t < 128) {
            float cm = cmaxb[px];
            int x = xt * PXB + px;
            #pragma unroll
            for (int k = 0; k < 3; ++k) {
                int d = j + 32 * k;
                out[((size_t)(b * D_ + d) * H_ + y) * W_ + x] = (v[k] == 0.0f) ? cm : v[k];
            }
        }
    }
}

// ---------------------------------------------------------------------------
extern "C" void kernel_launch(void* const* d_in, const int* in_sizes, int n_in,
                              void* d_out, int out_size, void* d_ws, size_t ws_size,
                              hipStream_t stream) {
    const float* cur        = (const float*)d_in[0];  // [B,C,H,W]
    const float* lf         = (const float*)d_in[1];  // [B,F,C,H,W]
    const float* poses      = (const float*)d_in[2];  // [B,F,4,4]
    const float* K          = (const float*)d_in[3];  // [B,4,4]
    const float* invK       = (const float*)d_in[4];  // [B,4,4]
    const float* depth_bins = (const float*)d_in[5];  // [D]
    float* out = (float*)d_out;
    float* ws  = (float*)d_ws;

    prep_kernel<<<NT_BLKS, 256, 0, stream>>>(cur, lf, ws);
    mega_kernel<<<B_ * H_ * XT_, 256, 0, stream>>>(poses, K, invK, depth_bins, ws, out);
}